// Round 8
// baseline (999.617 us; speedup 1.0000x reference)
//
#include <hip/hip_runtime.h>
#include <hip/hip_bf16.h>

#define NROW 778
#define NPAD 784     // 49*16
#define FDIM 128
#define KHID 256

typedef unsigned short u16;
typedef __attribute__((ext_vector_type(4))) unsigned int u32x4;
typedef __attribute__((ext_vector_type(4))) float f32x4;

__device__ __forceinline__ u16 f2bfu(float x) {
  return __builtin_bit_cast(u16, __float2bfloat16(x));
}
// HW-verified (round 1): A[row=lane&15][k=8*(lane>>4)+e], B[k=8*(lane>>4)+e][col=lane&15],
// D[row=4*(lane>>4)+r][col=lane&15]
__device__ __forceinline__ void mfma32(f32x4& d, const u32x4& a, const u32x4& b) {
  asm("v_mfma_f32_16x16x32_bf16 %0, %1, %2, %0" : "+v"(d) : "v"(a), "v"(b));
}

// ---------------- workspace layout (bytes) ---------------- (R1 verbatim)
#define WS_A    0u           // a[784][256] f32
#define WS_C    802816u      // c[784][256] f32
#define WS_XI   1605632u     // xi[784][128] f32
#define WS_XJ   2007040u     // xj[784][128] f32
#define WS_VJ   2408448u     // vj[784][128] f32
#define WS_S    2809856u     // S[784][128] f32
#define WS_INV  3211264u     // invS[784][128] f32
#define WS_AGG  3612672u     // agg[784][128] f32
#define WS_W2B  4014080u     // W2 frag-order bf16 [8][8][64][8]     (65536 B)
#define WS_C1B  4079616u     // conv1 frag-order bf16 [4][4][64][8]  (16384 B)
#define WS_C2B  4096000u     // conv2 frag-order bf16 [8][64][8]     (8192 B)
// end 4104192

__global__ void kzero(float* S, float* agg) {
  int idx = blockIdx.x * blockDim.x + threadIdx.x;
  if (idx < NPAD * FDIM) { S[idx] = 0.f; agg[idx] = 0.f; }
}

__global__ void kinv(const float* __restrict__ S, float* __restrict__ invS) {
  int idx = blockIdx.x * blockDim.x + threadIdx.x;
  if (idx >= NPAD * FDIM) return;
  int j = idx >> 7;
  invS[idx] = (j < NROW) ? 1.f / S[idx] : 0.f;
}

// Per-row projections (R1 verbatim)
__global__ void kprep_rows(const float* __restrict__ Lf, const float* __restrict__ Rf,
                           const float* __restrict__ lp, const float* __restrict__ rp,
                           const float* __restrict__ W1, const float* __restrict__ b1,
                           const float* __restrict__ b2,
                           const float* __restrict__ Wq, const float* __restrict__ bq,
                           const float* __restrict__ Wv, const float* __restrict__ bv,
                           const float* __restrict__ Wk, const float* __restrict__ bk,
                           float* __restrict__ a, float* __restrict__ c,
                           float* __restrict__ xi, float* __restrict__ xj,
                           float* __restrict__ vj) {
  __shared__ float sl[128], sr[128], slp[128], srp[128];
  const int row = blockIdx.x, t = threadIdx.x;
  if (t < 128) {
    sl[t] = Lf[row * 128 + t]; sr[t] = Rf[row * 128 + t];
    slp[t] = lp[row * 128 + t]; srp[t] = rp[row * 128 + t];
  }
  __syncthreads();
  float aa = 0.f, cc = 0.f;
  for (int k = 0; k < 128; ++k) {
    float w = W1[k * 256 + t];
    aa += slp[k] * w; cc += srp[k] * w;
  }
  a[row * 256 + t] = aa;
  c[row * 256 + t] = b1[t] - cc;
  if (t < 128) {
    float q = 0.f, kk = 0.f, vv = 0.f;
    for (int k = 0; k < 128; ++k) {
      float l = sl[k], r = sr[k];
      q  += l * Wq[k * 128 + t];
      vv += l * Wv[k * 128 + t];
      kk += r * Wk[k * 128 + t];
    }
    xi[row * 128 + t] = q + bq[t] + b2[t];
    xj[row * 128 + t] = -(kk + bk[t]);
    vj[row * 128 + t] = vv + bv[t] + b2[t];
  }
}

// Repack weights into MFMA fragment order (bf16) — R1 verbatim
__global__ void kprep_frags(const float* __restrict__ W2, const float* __restrict__ c1w,
                            const float* __restrict__ c2w,
                            u16* __restrict__ w2B, u16* __restrict__ c1B,
                            u16* __restrict__ c2B) {
  const int idx0 = blockIdx.x * blockDim.x + threadIdx.x;
  const int nthr = gridDim.x * blockDim.x;
  for (int idx = idx0; idx < 32768; idx += nthr) {
    int e = idx & 7, ln = (idx >> 3) & 63, n = (idx >> 9) & 7, ks = idx >> 12;
    int k = ks * 32 + ((ln >> 4) << 3) + e;
    int col = n * 16 + (ln & 15);
    w2B[idx] = f2bfu(W2[k * FDIM + col]);
  }
  for (int idx = idx0; idx < 8192; idx += nthr) {
    int e = idx & 7, ln = (idx >> 3) & 63, b = (idx >> 9) & 3, hp = idx >> 11;
    int k = ((ln >> 4) << 3) + e;
    int col = ln & 15;
    int hb = hp * 2 + (b >> 1);
    float v = ((k >> 4) == (b >> 1)) ? c1w[(hb * 32 + (b & 1) * 16 + col) * 16 + (k & 15)] : 0.f;
    c1B[idx] = f2bfu(v);
  }
  for (int idx = idx0; idx < 4096; idx += nthr) {
    int e = idx & 7, ln = (idx >> 3) & 63, h = idx >> 9;
    int o = ((ln >> 4) << 3) + e;
    int d = ln & 15;
    c2B[idx] = f2bfu(c2w[(h * 16 + d) * 32 + o]);
  }
}

// ---------------- main pair-tile kernel ----------------
// Grid (49, 5). PASS 0: blockIdx.x = j-tile, loop i-tiles t = s, s+5, ... ;
//               PASS 1: blockIdx.x = i-tile, loop j-tiles likewise.
// Per-tile math is R1-verbatim; only accumulation plumbing changed
// (register accumulators + one writeout instead of per-tile atomics).
template <int PASS>
__global__ __launch_bounds__(512, 2) void kpass(
    const float* __restrict__ ga, const float* __restrict__ gc,
    const float* __restrict__ gxi, const float* __restrict__ gxj,
    const float* __restrict__ gvj, const u16* __restrict__ gw2B,
    const u16* __restrict__ gc1B, const u16* __restrict__ gc2B,
    const float* __restrict__ gcb1, const float* __restrict__ gcb2,
    float* __restrict__ S, const float* __restrict__ invS, float* __restrict__ agg) {
  __shared__ __align__(16) char sm[155648];
  float* sA  = (float*)(sm + 0);        // [16][256] f32
  float* sCf = (float*)(sm + 16384);    // [8][64][8] f32
  float* sXj = (float*)(sm + 131072);   // [16][128] f32
  float* sIv = (float*)(sm + 139264);   // [16][128] f32 (pass1: invS tile)
  float* sVj = (float*)(sm + 147456);   // [16][128] f32 (pass1: vj tile)

  const int tid = threadIdx.x;
  const int lane = tid & 63;
  const int w = tid >> 6;
  const int jj = lane & 15, kg = lane >> 4;
  const int fix0 = blockIdx.x * 16;
  const int s = blockIdx.y;

  u16* myX = (u16*)(sm + 32768 + w * 12288);         // [4][64][8] bf16
  u16* myH = (u16*)(sm + 32768 + w * 12288 + 4096);  // [8][64][8] bf16
  const u32x4* w2v = (const u32x4*)gw2B;
  const u32x4* c1v = (const u32x4*)gc1B;
  const u32x4* c2v = (const u32x4*)gc2B;

  // ---- persistent staging (fixed-side) ----
  if (PASS == 0) {
    const int j0 = fix0;
    for (int idx = tid; idx < 4096; idx += 512) {  // sCf frag order
      int ks = idx >> 9, ln = (idx >> 3) & 63, e = idx & 7;
      int jr = j0 + (ln & 15); if (jr > NROW - 1) jr = NROW - 1;
      int k = ks * 32 + ((ln >> 4) << 3) + e;
      sCf[idx] = gc[jr * KHID + k];
    }
    for (int idx = tid; idx < 2048; idx += 512) {
      int row = idx >> 7, ch = idx & 127;
      int jr = j0 + row; if (jr > NROW - 1) jr = NROW - 1;
      sXj[idx] = gxj[jr * FDIM + ch];
    }
  } else {
    const int i0 = fix0;
    for (int idx = tid; idx < 4096; idx += 512) {  // sA row-major
      int row = idx >> 8;
      int ir = i0 + row; if (ir > NROW - 1) ir = NROW - 1;
      sA[idx] = ga[ir * KHID + (idx & 255)];
    }
  }

  float ssum[8][4];   // PASS0: per-lane S accum over (h, r)
  f32x4 asum[2][2];   // PASS1: per-lane agg accum, [mt][h/4 packed] x4 -> use array of 16
  float aacc[2][8];   // PASS1 accumulators (mt, h)
#pragma unroll
  for (int h = 0; h < 8; ++h)
#pragma unroll
    for (int r = 0; r < 4; ++r) ssum[h][r] = 0.f;
#pragma unroll
  for (int mt = 0; mt < 2; ++mt)
#pragma unroll
    for (int h = 0; h < 8; ++h) aacc[mt][h] = 0.f;
  (void)asum;

  // ---- tile loop ----
  for (int t = s; t < 49; t += 5) {
    const int i0 = (PASS == 0) ? t * 16 : fix0;
    const int j0 = (PASS == 0) ? fix0 : t * 16;
    // per-iter staging (varying side)
    if (PASS == 0) {
      for (int idx = tid; idx < 4096; idx += 512) {
        int row = idx >> 8;
        int ir = i0 + row; if (ir > NROW - 1) ir = NROW - 1;
        sA[idx] = ga[ir * KHID + (idx & 255)];
      }
    } else {
      for (int idx = tid; idx < 4096; idx += 512) {
        int ks = idx >> 9, ln = (idx >> 3) & 63, e = idx & 7;
        int jr = j0 + (ln & 15); if (jr > NROW - 1) jr = NROW - 1;
        int k = ks * 32 + ((ln >> 4) << 3) + e;
        sCf[idx] = gc[jr * KHID + k];
      }
      for (int idx = tid; idx < 2048; idx += 512) {
        int row = idx >> 7, ch = idx & 127;
        int jr = j0 + row; if (jr > NROW - 1) jr = NROW - 1;
        sXj[idx] = gxj[jr * FDIM + ch];
      }
      for (int idx = tid; idx < 2048; idx += 512) {
        int row = idx >> 7, ch = idx & 127;
        int jr = j0 + row;                 // invS rows >= NROW are true zeros
        sIv[idx] = invS[jr * FDIM + ch];
        int jc = jr > NROW - 1 ? NROW - 1 : jr;
        sVj[idx] = gvj[jc * FDIM + ch];
      }
    }
    __syncthreads();

    // ---- main GEMM (R1 verbatim) ----
    f32x4 acc[2][8];
#pragma unroll
    for (int mt = 0; mt < 2; ++mt)
#pragma unroll
      for (int n = 0; n < 8; ++n) acc[mt][n] = f32x4{0.f, 0.f, 0.f, 0.f};

#pragma unroll
    for (int ks = 0; ks < 8; ++ks) {
      const float4 c0 = *(const float4*)&sCf[(ks * 64 + lane) * 8];
      const float4 c1 = *(const float4*)&sCf[(ks * 64 + lane) * 8 + 4];
      const int ko = ks * 32 + kg * 8;
      u32x4 A[2];
#pragma unroll
      for (int mt = 0; mt < 2; ++mt) {
        const float4 a0 = *(const float4*)&sA[(2 * w + mt) * KHID + ko];
        const float4 a1 = *(const float4*)&sA[(2 * w + mt) * KHID + ko + 4];
        float h0 = fmaxf(a0.x + c0.x, 0.f), h1 = fmaxf(a0.y + c0.y, 0.f);
        float h2 = fmaxf(a0.z + c0.z, 0.f), h3 = fmaxf(a0.w + c0.w, 0.f);
        float h4 = fmaxf(a1.x + c1.x, 0.f), h5 = fmaxf(a1.y + c1.y, 0.f);
        float h6 = fmaxf(a1.z + c1.z, 0.f), h7 = fmaxf(a1.w + c1.w, 0.f);
        A[mt] = u32x4{(unsigned)f2bfu(h0) | ((unsigned)f2bfu(h1) << 16),
                      (unsigned)f2bfu(h2) | ((unsigned)f2bfu(h3) << 16),
                      (unsigned)f2bfu(h4) | ((unsigned)f2bfu(h5) << 16),
                      (unsigned)f2bfu(h6) | ((unsigned)f2bfu(h7) << 16)};
      }
#pragma unroll
      for (int n = 0; n < 8; ++n) {
        u32x4 B = w2v[(ks * 8 + n) * 64 + lane];
        mfma32(acc[0][n], A[0], B);
        mfma32(acc[1][n], A[1], B);
      }
    }

    // ---- per-wave conv + epilogue (R1 verbatim, reg accumulation) ----
#pragma unroll
    for (int mt = 0; mt < 2; ++mt) {
      const int i = i0 + 2 * w + mt;
      const int ic = i > NROW - 1 ? NROW - 1 : i;
      // x = rel_raw + xi[i] + xj[j] -> myX in conv1 A-frag order
#pragma unroll
      for (int n = 0; n < 8; ++n) {
        const int ch = n * 16 + jj;
        const float xiv = gxi[ic * FDIM + ch];
#pragma unroll
        for (int r = 0; r < 4; ++r) {
          const int prow = kg * 4 + r;
          float xv = acc[mt][n][r] + xiv + sXj[prow * FDIM + ch];
          int idxX = ((ch >> 5) * 512) + (prow + 16 * ((ch >> 3) & 3)) * 8 + (ch & 7);
          myX[idxX] = f2bfu(xv);
        }
      }
      // conv1 (2-head group, K=32 block diagonal)
#pragma unroll
      for (int hp = 0; hp < 4; ++hp) {
        u32x4 Ax = ((const u32x4*)myX)[hp * 64 + lane];
#pragma unroll
        for (int b = 0; b < 4; ++b) {
          u32x4 Bw = c1v[(hp * 4 + b) * 64 + lane];
          f32x4 hacc = f32x4{0.f, 0.f, 0.f, 0.f};
          mfma32(hacc, Ax, Bw);
          const int och = (hp * 2 + (b >> 1)) * 32 + (b & 1) * 16 + jj;
          const float bias = gcb1[och];
#pragma unroll
          for (int r = 0; r < 4; ++r) {
            const int prow = kg * 4 + r;
            float hv = fmaxf(hacc[r] + bias, 0.f);
            int idxH = ((och >> 5) * 512) + (prow + 16 * ((och >> 3) & 3)) * 8 + (och & 7);
            myH[idxH] = f2bfu(hv);
          }
        }
      }
      // conv2 + accumulation per head
#pragma unroll
      for (int h = 0; h < 8; ++h) {
        u32x4 Ah = ((const u32x4*)myH)[h * 64 + lane];
        u32x4 Bw = c2v[h * 64 + lane];
        f32x4 sacc = f32x4{0.f, 0.f, 0.f, 0.f};
        mfma32(sacc, Ah, Bw);
        const float bias = gcb2[h * 16 + jj];
        if (PASS == 0) {
          if (i < NROW) {
#pragma unroll
            for (int r = 0; r < 4; ++r) {
              ssum[h][r] += __expf(sacc[r] + bias);
            }
          }
        } else {
          float sum = 0.f;
#pragma unroll
          for (int r = 0; r < 4; ++r) {
            const int prow = kg * 4 + r;
            float e = __expf(sacc[r] + bias);
            float iv = sIv[prow * FDIM + h * 16 + jj];   // 0 for padded j
            float vv = acc[mt][h][r] + sVj[prow * FDIM + h * 16 + jj];
            sum += e * iv * vv;
          }
          sum += __shfl_xor(sum, 16);
          sum += __shfl_xor(sum, 32);
          aacc[mt][h] += sum;
        }
      }
    }
    __syncthreads();   // protect per-iter staged LDS from next iteration
  }

  // ---- writeout ----
  if (PASS == 0) {
    // 8-wave combine via plain LDS strips (sA/sCf/early wave bufs are dead)
    float* strips = (float*)sm;   // [8][2048]
#pragma unroll
    for (int h = 0; h < 8; ++h)
#pragma unroll
      for (int r = 0; r < 4; ++r)
        strips[w * 2048 + (kg * 4 + r) * FDIM + h * 16 + jj] = ssum[h][r];
    __syncthreads();
    const int j0 = fix0;
    for (int idx = tid; idx < 2048; idx += 512) {
      float v = 0.f;
#pragma unroll
      for (int ww = 0; ww < 8; ++ww) v += strips[ww * 2048 + idx];
      atomicAdd(&S[(j0 + (idx >> 7)) * FDIM + (idx & 127)], v);
    }
  } else {
    const int i0 = fix0;
#pragma unroll
    for (int mt = 0; mt < 2; ++mt) {
      const int i = i0 + 2 * w + mt;
#pragma unroll
      for (int h = 0; h < 8; ++h) {
        if (lane < 16) atomicAdd(&agg[i * FDIM + h * 16 + lane], aacc[mt][h]);
      }
    }
  }
}

// y = Lf + agg; out = y + fc2(relu(fc1(LN(y))))  (R1 verbatim)
__global__ void kfinal(const float* __restrict__ Lf, const float* __restrict__ agg,
                       const float* __restrict__ g, const float* __restrict__ b,
                       const float* __restrict__ W1, const float* __restrict__ b1,
                       const float* __restrict__ W2, const float* __restrict__ b2,
                       float* __restrict__ out) {
  __shared__ float sY[128], sYn[128], sH[256], sStat[2];
  const int row = blockIdx.x, t = threadIdx.x;
  if (t < 128) sY[t] = Lf[row * 128 + t] + agg[row * 128 + t];
  __syncthreads();
  if (t < 64) {
    float y0 = sY[t], y1 = sY[t + 64];
    float s = y0 + y1, s2 = y0 * y0 + y1 * y1;
#pragma unroll
    for (int off = 32; off; off >>= 1) {
      s += __shfl_down(s, off);
      s2 += __shfl_down(s2, off);
    }
    if (t == 0) {
      float mu = s * (1.f / 128.f);
      float var = s2 * (1.f / 128.f) - mu * mu;
      sStat[0] = mu;
      sStat[1] = rsqrtf(var + 1e-6f);
    }
  }
  __syncthreads();
  if (t < 128) sYn[t] = (sY[t] - sStat[0]) * sStat[1] * g[t] + b[t];
  __syncthreads();
  float ha = b1[t];
  for (int k = 0; k < 128; ++k) ha += sYn[k] * W1[k * 256 + t];
  sH[t] = fmaxf(ha, 0.f);
  __syncthreads();
  if (t < 128) {
    float oa = b2[t];
    for (int k = 0; k < 256; ++k) oa += sH[k] * W2[k * 128 + t];
    out[row * 128 + t] = sY[t] + oa;
  }
}

extern "C" void kernel_launch(void* const* d_in, const int* in_sizes, int n_in,
                              void* d_out, int out_size, void* d_ws, size_t ws_size,
                              hipStream_t stream) {
  const float* Lf  = (const float*)d_in[0];
  const float* Rf  = (const float*)d_in[1];
  const float* lp  = (const float*)d_in[2];
  const float* rp  = (const float*)d_in[3];
  const float* pW1 = (const float*)d_in[4];
  const float* pb1 = (const float*)d_in[5];
  const float* pW2 = (const float*)d_in[6];
  const float* pb2 = (const float*)d_in[7];
  const float* Wq  = (const float*)d_in[8];
  const float* bq  = (const float*)d_in[9];
  const float* Wv  = (const float*)d_in[10];
  const float* bv  = (const float*)d_in[11];
  const float* Wk  = (const float*)d_in[12];
  const float* bk  = (const float*)d_in[13];
  const float* c1w = (const float*)d_in[14];
  const float* c1b = (const float*)d_in[15];
  const float* c2w = (const float*)d_in[16];
  const float* c2b = (const float*)d_in[17];
  const float* lng = (const float*)d_in[18];
  const float* lnb = (const float*)d_in[19];
  const float* fW1 = (const float*)d_in[20];
  const float* fb1 = (const float*)d_in[21];
  const float* fW2 = (const float*)d_in[22];
  const float* fb2 = (const float*)d_in[23];
  float* out = (float*)d_out;
  char* ws = (char*)d_ws;

  float* a    = (float*)(ws + WS_A);
  float* c    = (float*)(ws + WS_C);
  float* xi   = (float*)(ws + WS_XI);
  float* xj   = (float*)(ws + WS_XJ);
  float* vj   = (float*)(ws + WS_VJ);
  float* S    = (float*)(ws + WS_S);
  float* invS = (float*)(ws + WS_INV);
  float* agg  = (float*)(ws + WS_AGG);
  u16* w2B = (u16*)(ws + WS_W2B);
  u16* c1B = (u16*)(ws + WS_C1B);
  u16* c2B = (u16*)(ws + WS_C2B);

  kzero<<<dim3((NPAD * FDIM + 511) / 512), dim3(512), 0, stream>>>(S, agg);
  kprep_rows<<<dim3(NROW), dim3(256), 0, stream>>>(Lf, Rf, lp, rp, pW1, pb1, pb2,
                                                   Wq, bq, Wv, bv, Wk, bk,
                                                   a, c, xi, xj, vj);
  kprep_frags<<<dim3(16), dim3(512), 0, stream>>>(pW2, c1w, c2w, w2B, c1B, c2B);

  kpass<0><<<dim3(49, 5), dim3(512), 0, stream>>>(a, c, xi, xj, vj, w2B, c1B, c2B,
                                                  c1b, c2b, S, invS, agg);
  kinv<<<dim3((NPAD * FDIM + 511) / 512), dim3(512), 0, stream>>>(S, invS);
  kpass<1><<<dim3(49, 5), dim3(512), 0, stream>>>(a, c, xi, xj, vj, w2B, c1B, c2B,
                                                  c1b, c2b, S, invS, agg);
  kfinal<<<dim3(NROW), dim3(256), 0, stream>>>(Lf, agg, lng, lnb, fW1, fb1, fW2, fb2, out);
}

// Round 9
// 809.721 us; speedup vs baseline: 1.2345x; 1.2345x over previous
//
#include <hip/hip_runtime.h>
#include <hip/hip_bf16.h>

#define NROW 778
#define NPAD 784     // 49*16
#define FDIM 128
#define KHID 256

typedef unsigned short u16;
typedef __attribute__((ext_vector_type(4))) unsigned int u32x4;
typedef __attribute__((ext_vector_type(4))) float f32x4;

__device__ __forceinline__ u16 f2bfu(float x) {
  return __builtin_bit_cast(u16, __float2bfloat16(x));
}
__device__ __forceinline__ unsigned pk2(float lo, float hi) {
  return (unsigned)f2bfu(lo) | ((unsigned)f2bfu(hi) << 16);
}
// HW-verified: A[row=lane&15][k=8*(lane>>4)+e], B[k=8*(lane>>4)+e][col=lane&15],
// D[row=4*(lane>>4)+r][col=lane&15]
__device__ __forceinline__ void mfma32(f32x4& d, const u32x4& a, const u32x4& b) {
  asm("v_mfma_f32_16x16x32_bf16 %0, %1, %2, %0" : "+v"(d) : "v"(a), "v"(b));
}

// ---------------- workspace layout (bytes) ---------------- (R1 verbatim)
#define WS_A    0u
#define WS_C    802816u
#define WS_XI   1605632u
#define WS_XJ   2007040u
#define WS_VJ   2408448u
#define WS_S    2809856u
#define WS_INV  3211264u
#define WS_AGG  3612672u
#define WS_W2B  4014080u
#define WS_C1B  4079616u
#define WS_C2B  4096000u
// end 4104192

// ---------------- kpass LDS map (bytes) ----------------
#define SMO_CF   0        // f32 [8][64][8]      16384
#define SMO_XI   16384    // f32 [16][132]        8448
#define SMO_XJ   24832    // f32 [16][132]        8448
#define SMO_IV   33280    // PASS1 invS / PASS0 sSp  8448
#define SMO_VJ   41728    // f32 [16][132]        8448
#define SMO_B1   50176    // f32 [256]            1024
#define SMO_B2   51200    // f32 [128]             512
#define SMO_WV   51712    // per-wave 12800 x 8 = 102400
#define SMO_TOT  154112

__global__ void kzero(float* S, float* agg) {
  int idx = blockIdx.x * blockDim.x + threadIdx.x;
  if (idx < NPAD * FDIM) { S[idx] = 0.f; agg[idx] = 0.f; }
}

__global__ void kinv(const float* __restrict__ S, float* __restrict__ invS) {
  int idx = blockIdx.x * blockDim.x + threadIdx.x;
  if (idx >= NPAD * FDIM) return;
  int j = idx >> 7;
  invS[idx] = (j < NROW) ? 1.f / S[idx] : 0.f;
}

// Per-row projections (R1 verbatim)
__global__ void kprep_rows(const float* __restrict__ Lf, const float* __restrict__ Rf,
                           const float* __restrict__ lp, const float* __restrict__ rp,
                           const float* __restrict__ W1, const float* __restrict__ b1,
                           const float* __restrict__ b2,
                           const float* __restrict__ Wq, const float* __restrict__ bq,
                           const float* __restrict__ Wv, const float* __restrict__ bv,
                           const float* __restrict__ Wk, const float* __restrict__ bk,
                           float* __restrict__ a, float* __restrict__ c,
                           float* __restrict__ xi, float* __restrict__ xj,
                           float* __restrict__ vj) {
  __shared__ float sl[128], sr[128], slp[128], srp[128];
  const int row = blockIdx.x, t = threadIdx.x;
  if (t < 128) {
    sl[t] = Lf[row * 128 + t]; sr[t] = Rf[row * 128 + t];
    slp[t] = lp[row * 128 + t]; srp[t] = rp[row * 128 + t];
  }
  __syncthreads();
  float aa = 0.f, cc = 0.f;
  for (int k = 0; k < 128; ++k) {
    float w = W1[k * 256 + t];
    aa += slp[k] * w; cc += srp[k] * w;
  }
  a[row * 256 + t] = aa;
  c[row * 256 + t] = b1[t] - cc;
  if (t < 128) {
    float q = 0.f, kk = 0.f, vv = 0.f;
    for (int k = 0; k < 128; ++k) {
      float l = sl[k], r = sr[k];
      q  += l * Wq[k * 128 + t];
      vv += l * Wv[k * 128 + t];
      kk += r * Wk[k * 128 + t];
    }
    xi[row * 128 + t] = q + bq[t] + b2[t];
    xj[row * 128 + t] = -(kk + bk[t]);
    vj[row * 128 + t] = vv + bv[t] + b2[t];
  }
}

// Frag tables (R1 verbatim)
__global__ void kprep_frags(const float* __restrict__ W2, const float* __restrict__ c1w,
                            const float* __restrict__ c2w,
                            u16* __restrict__ w2B, u16* __restrict__ c1B,
                            u16* __restrict__ c2B) {
  const int idx0 = blockIdx.x * blockDim.x + threadIdx.x;
  const int nthr = gridDim.x * blockDim.x;
  for (int idx = idx0; idx < 32768; idx += nthr) {
    int e = idx & 7, ln = (idx >> 3) & 63, n = (idx >> 9) & 7, ks = idx >> 12;
    int k = ks * 32 + ((ln >> 4) << 3) + e;
    int col = n * 16 + (ln & 15);
    w2B[idx] = f2bfu(W2[k * FDIM + col]);
  }
  for (int idx = idx0; idx < 8192; idx += nthr) {
    int e = idx & 7, ln = (idx >> 3) & 63, b = (idx >> 9) & 3, hp = idx >> 11;
    int k = ((ln >> 4) << 3) + e;
    int col = ln & 15;
    int hb = hp * 2 + (b >> 1);
    float v = ((k >> 4) == (b >> 1)) ? c1w[(hb * 32 + (b & 1) * 16 + col) * 16 + (k & 15)] : 0.f;
    c1B[idx] = f2bfu(v);
  }
  for (int idx = idx0; idx < 4096; idx += nthr) {
    int e = idx & 7, ln = (idx >> 3) & 63, h = idx >> 9;
    int o = ((ln >> 4) << 3) + e;
    int d = ln & 15;
    c2B[idx] = f2bfu(c2w[(h * 16 + d) * 32 + o]);
  }
}

// ---------------- main pair-tile kernel (R8 math, compact code) ----------------
// Grid (49,5). PASS 0: blockIdx.x = j-tile, loop i-tiles; PASS 1: i-tile, loop j-tiles.
template <int PASS>
__global__ __launch_bounds__(512, 2) void kpass(
    const float* __restrict__ ga, const float* __restrict__ gc,
    const float* __restrict__ gxi, const float* __restrict__ gxj,
    const float* __restrict__ gvj, const u16* __restrict__ gw2B,
    const u16* __restrict__ gc1B, const u16* __restrict__ gc2B,
    const float* __restrict__ gcb1, const float* __restrict__ gcb2,
    float* __restrict__ S, const float* __restrict__ invS, float* __restrict__ agg) {
  __shared__ __align__(16) char sm[SMO_TOT];
  float* sCf = (float*)(sm + SMO_CF);
  float* sXi = (float*)(sm + SMO_XI);
  float* sXj = (float*)(sm + SMO_XJ);
  float* sIv = (float*)(sm + SMO_IV);   // PASS0: sSp accumulator
  float* sVj = (float*)(sm + SMO_VJ);
  float* sB1 = (float*)(sm + SMO_B1);
  float* sB2 = (float*)(sm + SMO_B2);

  const int tid = threadIdx.x;
  const int lane = tid & 63;
  const int w = tid >> 6;
  const int jj = lane & 15, kg = lane >> 4;
  const int fix0 = blockIdx.x * 16;
  const int s = blockIdx.y;

  float* relw  = (float*)(sm + SMO_WV + w * 12800);          // [16][132] f32
  float* hldsw = (float*)(sm + SMO_WV + w * 12800 + 8448);   // [16][68]  f32
  const u32x4* w2v = (const u32x4*)gw2B;
  const u32x4* c1v = (const u32x4*)gc1B;
  const u32x4* c2v = (const u32x4*)gc2B;

  // ---- once-per-block staging ----
  if (tid < 256) sB1[tid] = gcb1[tid];
  else if (tid < 384) sB2[tid - 256] = gcb2[tid - 256];
  if (PASS == 0) {
    const int j0 = fix0;
    for (int idx = tid; idx < 4096; idx += 512) {     // sCf frag order (R8 verbatim)
      int ks = idx >> 9, ln = (idx >> 3) & 63, e = idx & 7;
      int jr = j0 + (ln & 15); if (jr > NROW - 1) jr = NROW - 1;
      int k = ks * 32 + ((ln >> 4) << 3) + e;
      sCf[idx] = gc[jr * KHID + k];
    }
    for (int idx = tid; idx < 512; idx += 512) {      // sXj vectorized
      int row = idx >> 5, c4 = (idx & 31) << 2;
      int jr = j0 + row; if (jr > NROW - 1) jr = NROW - 1;
      *(float4*)&sXj[row * 132 + c4] = *(const float4*)&gxj[(size_t)jr * FDIM + c4];
    }
    for (int idx = tid; idx < 2048; idx += 512)       // sSp init
      sIv[(idx >> 7) * 132 + (idx & 127)] = 0.f;
  } else {
    const int i0 = fix0;
    for (int idx = tid; idx < 512; idx += 512) {      // sXi once (i fixed)
      int row = idx >> 5, c4 = (idx & 31) << 2;
      int ir = i0 + row; if (ir > NROW - 1) ir = NROW - 1;
      *(float4*)&sXi[row * 132 + c4] = *(const float4*)&gxi[(size_t)ir * FDIM + c4];
    }
  }

  // ---- tile loop ----
#pragma unroll 1
  for (int t = s; t < 49; t += 5) {
    const int i0 = (PASS == 0) ? t * 16 : fix0;
    const int j0 = (PASS == 0) ? fix0 : t * 16;
    if (PASS == 0) {
      for (int idx = tid; idx < 512; idx += 512) {    // sXi per tile
        int row = idx >> 5, c4 = (idx & 31) << 2;
        int ir = i0 + row; if (ir > NROW - 1) ir = NROW - 1;
        *(float4*)&sXi[row * 132 + c4] = *(const float4*)&gxi[(size_t)ir * FDIM + c4];
      }
    } else {
      for (int idx = tid; idx < 4096; idx += 512) {   // sCf per tile
        int ks = idx >> 9, ln = (idx >> 3) & 63, e = idx & 7;
        int jr = j0 + (ln & 15); if (jr > NROW - 1) jr = NROW - 1;
        int k = ks * 32 + ((ln >> 4) << 3) + e;
        sCf[idx] = gc[jr * KHID + k];
      }
      for (int idx = tid; idx < 512; idx += 512) {
        int row = idx >> 5, c4 = (idx & 31) << 2;
        int jr = j0 + row;
        int jc = jr > NROW - 1 ? NROW - 1 : jr;
        *(float4*)&sXj[row * 132 + c4] = *(const float4*)&gxj[(size_t)jc * FDIM + c4];
        *(float4*)&sIv[row * 132 + c4] = *(const float4*)&invS[(size_t)jr * FDIM + c4]; // 0-padded rows
        *(float4*)&sVj[row * 132 + c4] = *(const float4*)&gvj[(size_t)jc * FDIM + c4];
      }
    }
    __syncthreads();

    const int iw = i0 + 2 * w;
    const int ic0 = iw < NROW ? iw : NROW - 1;
    const int ic1 = iw + 1 < NROW ? iw + 1 : NROW - 1;
    const float* ar0 = ga + (size_t)ic0 * KHID;
    const float* ar1 = ga + (size_t)ic1 * KHID;

    // ---- GEMM (rolled ks; math = R8 verbatim) ----
    f32x4 acc[2][8];
#pragma unroll
    for (int mt = 0; mt < 2; ++mt)
#pragma unroll
      for (int n = 0; n < 8; ++n) acc[mt][n] = f32x4{0.f, 0.f, 0.f, 0.f};

#pragma unroll 1
    for (int ks = 0; ks < 8; ++ks) {
      const float4 c0 = *(const float4*)&sCf[(ks * 64 + lane) * 8];
      const float4 c1 = *(const float4*)&sCf[(ks * 64 + lane) * 8 + 4];
      const int kb = ks * 32 + 8 * kg;
      const float4 a0 = *(const float4*)(ar0 + kb);
      const float4 a1 = *(const float4*)(ar0 + kb + 4);
      const float4 b0 = *(const float4*)(ar1 + kb);
      const float4 b1 = *(const float4*)(ar1 + kb + 4);
      u32x4 A0 = u32x4{pk2(fmaxf(a0.x + c0.x, 0.f), fmaxf(a0.y + c0.y, 0.f)),
                       pk2(fmaxf(a0.z + c0.z, 0.f), fmaxf(a0.w + c0.w, 0.f)),
                       pk2(fmaxf(a1.x + c1.x, 0.f), fmaxf(a1.y + c1.y, 0.f)),
                       pk2(fmaxf(a1.z + c1.z, 0.f), fmaxf(a1.w + c1.w, 0.f))};
      u32x4 A1 = u32x4{pk2(fmaxf(b0.x + c0.x, 0.f), fmaxf(b0.y + c0.y, 0.f)),
                       pk2(fmaxf(b0.z + c0.z, 0.f), fmaxf(b0.w + c0.w, 0.f)),
                       pk2(fmaxf(b1.x + c1.x, 0.f), fmaxf(b1.y + c1.y, 0.f)),
                       pk2(fmaxf(b1.z + c1.z, 0.f), fmaxf(b1.w + c1.w, 0.f))};
#pragma unroll
      for (int n = 0; n < 8; ++n) {
        u32x4 B = w2v[(ks * 8 + n) * 64 + lane];
        mfma32(acc[0][n], A0, B);
        mfma32(acc[1][n], A1, B);
      }
    }

    // ---- conv + epilogue (rolled loops; per-wave f32 LDS transpose) ----
#pragma unroll
    for (int mt = 0; mt < 2; ++mt) {
      const int i = iw + mt;
      const int irow = 2 * w + mt;
      // spill rel tile (f32, [j=prow][ch]) — static acc indices
#pragma unroll
      for (int n = 0; n < 8; ++n)
#pragma unroll
        for (int r = 0; r < 4; ++r)
          relw[(4 * kg + r) * 132 + n * 16 + jj] = acc[mt][n][r];

#pragma unroll 1
      for (int hp = 0; hp < 4; ++hp) {
        // conv1 A-frag: x[j=jj][ch=hp*32+8kg+e] = rel + xi + xj  (same bits as R8)
        const int cb = hp * 32 + 8 * kg;
        const float4 r0 = *(const float4*)&relw[jj * 132 + cb];
        const float4 r1 = *(const float4*)&relw[jj * 132 + cb + 4];
        const float4 xi0 = *(const float4*)&sXi[irow * 132 + cb];
        const float4 xi1 = *(const float4*)&sXi[irow * 132 + cb + 4];
        const float4 xj0 = *(const float4*)&sXj[jj * 132 + cb];
        const float4 xj1 = *(const float4*)&sXj[jj * 132 + cb + 4];
        u32x4 Ax = u32x4{pk2(r0.x + xi0.x + xj0.x, r0.y + xi0.y + xj0.y),
                         pk2(r0.z + xi0.z + xj0.z, r0.w + xi0.w + xj0.w),
                         pk2(r1.x + xi1.x + xj1.x, r1.y + xi1.y + xj1.y),
                         pk2(r1.z + xi1.z + xj1.z, r1.w + xi1.w + xj1.w)};
        // conv1: 4 b-tiles (block-diag 2-head, K=32)
#pragma unroll 1
        for (int b = 0; b < 4; ++b) {
          u32x4 Bw = c1v[(hp * 4 + b) * 64 + lane];
          f32x4 hacc = f32x4{0.f, 0.f, 0.f, 0.f};
          mfma32(hacc, Ax, Bw);
          const int ochl = (b >> 1) * 32 + (b & 1) * 16 + jj;   // within-hp 0..63
          const float bias = sB1[hp * 64 + ochl];
#pragma unroll
          for (int r = 0; r < 4; ++r)
            hldsw[(4 * kg + r) * 68 + ochl] = fmaxf(hacc[r] + bias, 0.f);
        }
        // conv2 + softmax epilogue per local head
#pragma unroll 1
        for (int hh = 0; hh < 2; ++hh) {
          const int h = hp * 2 + hh;
          const int ob = hh * 32 + 8 * kg;
          const float4 h0 = *(const float4*)&hldsw[jj * 68 + ob];
          const float4 h1 = *(const float4*)&hldsw[jj * 68 + ob + 4];
          u32x4 Ah = u32x4{pk2(h0.x, h0.y), pk2(h0.z, h0.w),
                           pk2(h1.x, h1.y), pk2(h1.z, h1.w)};
          u32x4 Bw = c2v[h * 64 + lane];
          f32x4 sacc = f32x4{0.f, 0.f, 0.f, 0.f};
          mfma32(sacc, Ah, Bw);
          const float bias = sB2[h * 16 + jj];
          if (PASS == 0) {
            if (i < NROW) {
#pragma unroll
              for (int r = 0; r < 4; ++r) {
                float e = __expf(sacc[r] + bias);
                atomicAdd(&sIv[(4 * kg + r) * 132 + h * 16 + jj], e);   // sSp
              }
            }
          } else {
            float sum = 0.f;
#pragma unroll
            for (int r = 0; r < 4; ++r) {
              const int prow = 4 * kg + r;
              float e = __expf(sacc[r] + bias);
              float iv = sIv[prow * 132 + h * 16 + jj];        // 0 for padded j
              float vv = relw[prow * 132 + h * 16 + jj] + sVj[prow * 132 + h * 16 + jj];
              sum += e * iv * vv;
            }
            sum += __shfl_xor(sum, 16);
            sum += __shfl_xor(sum, 32);
            if (lane < 16) atomicAdd(&agg[(size_t)i * FDIM + h * 16 + lane], sum);
          }
        }
      }
    }
    __syncthreads();   // protect staged LDS before next iteration
  }

  // ---- PASS0 writeout ----
  if (PASS == 0) {
    const int j0 = fix0;
    for (int idx = tid; idx < 2048; idx += 512) {
      int row = idx >> 7, col = idx & 127;
      atomicAdd(&S[(size_t)(j0 + row) * FDIM + col], sIv[row * 132 + col]);
    }
  }
}

// y = Lf + agg; out = y + fc2(relu(fc1(LN(y))))  (R1 verbatim)
__global__ void kfinal(const float* __restrict__ Lf, const float* __restrict__ agg,
                       const float* __restrict__ g, const float* __restrict__ b,
                       const float* __restrict__ W1, const float* __restrict__ b1,
                       const float* __restrict__ W2, const float* __restrict__ b2,
                       float* __restrict__ out) {
  __shared__ float sY[128], sYn[128], sH[256], sStat[2];
  const int row = blockIdx.x, t = threadIdx.x;
  if (t < 128) sY[t] = Lf[row * 128 + t] + agg[row * 128 + t];
  __syncthreads();
  if (t < 64) {
    float y0 = sY[t], y1 = sY[t + 64];
    float s = y0 + y1, s2 = y0 * y0 + y1 * y1;
#pragma unroll
    for (int off = 32; off; off >>= 1) {
      s += __shfl_down(s, off);
      s2 += __shfl_down(s2, off);
    }
    if (t == 0) {
      float mu = s * (1.f / 128.f);
      float var = s2 * (1.f / 128.f) - mu * mu;
      sStat[0] = mu;
      sStat[1] = rsqrtf(var + 1e-6f);
    }
  }
  __syncthreads();
  if (t < 128) sYn[t] = (sY[t] - sStat[0]) * sStat[1] * g[t] + b[t];
  __syncthreads();
  float ha = b1[t];
  for (int k = 0; k < 128; ++k) ha += sYn[k] * W1[k * 256 + t];
  sH[t] = fmaxf(ha, 0.f);
  __syncthreads();
  if (t < 128) {
    float oa = b2[t];
    for (int k = 0; k < 256; ++k) oa += sH[k] * W2[k * 128 + t];
    out[row * 128 + t] = sY[t] + oa;
  }
}

extern "C" void kernel_launch(void* const* d_in, const int* in_sizes, int n_in,
                              void* d_out, int out_size, void* d_ws, size_t ws_size,
                              hipStream_t stream) {
  const float* Lf  = (const float*)d_in[0];
  const float* Rf  = (const float*)d_in[1];
  const float* lp  = (const float*)d_in[2];
  const float* rp  = (const float*)d_in[3];
  const float* pW1 = (const float*)d_in[4];
  const float* pb1 = (const float*)d_in[5];
  const float* pW2 = (const float*)d_in[6];
  const float* pb2 = (const float*)d_in[7];
  const float* Wq  = (const float*)d_in[8];
  const float* bq  = (const float*)d_in[9];
  const float* Wv  = (const float*)d_in[10];
  const float* bv  = (const float*)d_in[11];
  const float* Wk  = (const float*)d_in[12];
  const float* bk  = (const float*)d_in[13];
  const float* c1w = (const float*)d_in[14];
  const float* c1b = (const float*)d_in[15];
  const float* c2w = (const float*)d_in[16];
  const float* c2b = (const float*)d_in[17];
  const float* lng = (const float*)d_in[18];
  const float* lnb = (const float*)d_in[19];
  const float* fW1 = (const float*)d_in[20];
  const float* fb1 = (const float*)d_in[21];
  const float* fW2 = (const float*)d_in[22];
  const float* fb2 = (const float*)d_in[23];
  float* out = (float*)d_out;
  char* ws = (char*)d_ws;

  float* a    = (float*)(ws + WS_A);
  float* c    = (float*)(ws + WS_C);
  float* xi   = (float*)(ws + WS_XI);
  float* xj   = (float*)(ws + WS_XJ);
  float* vj   = (float*)(ws + WS_VJ);
  float* S    = (float*)(ws + WS_S);
  float* invS = (float*)(ws + WS_INV);
  float* agg  = (float*)(ws + WS_AGG);
  u16* w2B = (u16*)(ws + WS_W2B);
  u16* c1B = (u16*)(ws + WS_C1B);
  u16* c2B = (u16*)(ws + WS_C2B);

  kzero<<<dim3((NPAD * FDIM + 511) / 512), dim3(512), 0, stream>>>(S, agg);
  kprep_rows<<<dim3(NROW), dim3(256), 0, stream>>>(Lf, Rf, lp, rp, pW1, pb1, pb2,
                                                   Wq, bq, Wv, bv, Wk, bk,
                                                   a, c, xi, xj, vj);
  kprep_frags<<<dim3(16), dim3(512), 0, stream>>>(pW2, c1w, c2w, w2B, c1B, c2B);

  kpass<0><<<dim3(49, 5), dim3(512), 0, stream>>>(a, c, xi, xj, vj, w2B, c1B, c2B,
                                                  c1b, c2b, S, invS, agg);
  kinv<<<dim3((NPAD * FDIM + 511) / 512), dim3(512), 0, stream>>>(S, invS);
  kpass<1><<<dim3(49, 5), dim3(512), 0, stream>>>(a, c, xi, xj, vj, w2B, c1B, c2B,
                                                  c1b, c2b, S, invS, agg);
  kfinal<<<dim3(NROW), dim3(256), 0, stream>>>(Lf, agg, lng, lnb, fW1, fb1, fW2, fb2, out);
}